// Round 3
// baseline (623.896 us; speedup 1.0000x reference)
//
#include <hip/hip_runtime.h>
#include <stdint.h>

typedef __bf16 bf16;
typedef bf16 bf16x8 __attribute__((ext_vector_type(8)));
typedef float f32x4 __attribute__((ext_vector_type(4)));
typedef unsigned short u16x8 __attribute__((ext_vector_type(8)));

__device__ __forceinline__ void gload_lds16(const bf16* g, bf16* l) {
    __builtin_amdgcn_global_load_lds(
        (const __attribute__((address_space(1))) void*)g,
        (__attribute__((address_space(3))) void*)l, 16, 0, 0);
}

// ---------------------------------------------------------------------------
// Prep: convert+transpose weights w1..w12 from fp32 (O,C,K) to bf16 [O][K*C]
// (r = k*C + c ordering). Coalesced: thread owns one (o, c-pair); 5x float4
// contiguous loads, register transpose, ushort2-packed stores at k*C stride.
// ---------------------------------------------------------------------------
template<int C>
__device__ __forceinline__ void cvt_pair(const float* __restrict__ src,
                                         bf16* __restrict__ dst,
                                         int tp, int base5)
{
    int ocp = tp - base5;          // pair index; oc = 2*ocp
    int oc  = ocp * 2;             // = o*C + c  (c even)
    int o   = oc / C;              // C is power of 2 -> shift
    int c   = oc & (C - 1);
    const f32x4* s4 = (const f32x4*)(src + (size_t)oc * 10);  // 80B-aligned
    float v[20];                   // v[0..9] = channel c, v[10..19] = c+1
#pragma unroll
    for (int j = 0; j < 5; j++) {
        f32x4 p = s4[j];
#pragma unroll
        for (int e = 0; e < 4; e++) v[4 * j + e] = p[e];
    }
    unsigned short* d = (unsigned short*)(dst + (size_t)base5 * 20
                                              + (size_t)o * 10 * C + c);
#pragma unroll
    for (int k = 0; k < 10; k++) {
        union { bf16 h; unsigned short u; } a, b;
        a.h = (bf16)v[k];
        b.h = (bf16)v[10 + k];
        uint32_t pk = (uint32_t)a.u | ((uint32_t)b.u << 16);
        *(uint32_t*)(d + (size_t)k * C) = pk;
    }
}

__global__ __launch_bounds__(256) void prep_w(
    const float* w1, const float* w2, const float* w3, const float* w4,
    const float* w5, const float* w6, const float* w7, const float* w8,
    const float* w9, const float* w10, const float* w11, const float* w12,
    bf16* __restrict__ dst)
{
    int t = blockIdx.x * 256 + threadIdx.x;   // pair index, total 817152
    if (t >= 817152) return;
    if      (t <   2048) cvt_pair< 64>(w1,  dst, t, 0);
    else if (t <   6144) cvt_pair< 64>(w2,  dst, t, 2048);
    else if (t <  14336) cvt_pair<128>(w3,  dst, t, 6144);
    else if (t <  30720) cvt_pair<128>(w4,  dst, t, 14336);
    else if (t <  63488) cvt_pair<256>(w5,  dst, t, 30720);
    else if (t <  96256) cvt_pair<256>(w6,  dst, t, 63488);
    else if (t < 161792) cvt_pair<256>(w7,  dst, t, 96256);
    else if (t < 292864) cvt_pair<512>(w8,  dst, t, 161792);
    else if (t < 423936) cvt_pair<512>(w9,  dst, t, 292864);
    else if (t < 555008) cvt_pair<512>(w10, dst, t, 423936);
    else if (t < 686080) cvt_pair<512>(w11, dst, t, 555008);
    else                 cvt_pair<512>(w12, dst, t, 686080);
}

// ---------------------------------------------------------------------------
// conv0: C=3, K=10, O=64, fp32 VALU. out: [2][81920][64] bf16
// ---------------------------------------------------------------------------
__global__ __launch_bounds__(256) void conv0_kernel(
    const float* __restrict__ x, const float* __restrict__ w0,
    const float* __restrict__ b0, const int* __restrict__ table,
    bf16* __restrict__ out)
{
    const int N = 81920;
    __shared__ float wls[30][64];
    __shared__ float bls[64];
    int tid = threadIdx.x;
    for (int i = tid; i < 1920; i += 256) {
        int o = i / 30, ck = i - o * 30;
        wls[ck][o] = w0[i];
    }
    if (tid < 64) bls[tid] = b0[tid];
    __syncthreads();

    int p = blockIdx.x * 256 + tid;
    int b = p >= N;
    int n = p - b * N;
    int idx[10];
    const int* trow = table + n * 10;
#pragma unroll
    for (int k = 0; k < 10; k++) idx[k] = trow[k];
    float xv[30];
#pragma unroll
    for (int c = 0; c < 3; c++)
#pragma unroll
        for (int k = 0; k < 10; k++)
            xv[c * 10 + k] = x[(b * 3 + c) * N + idx[k]];

    float acc[64];
#pragma unroll
    for (int o = 0; o < 64; o++) acc[o] = bls[o];
    for (int ck = 0; ck < 30; ck++) {
        float xs = xv[ck];
        const f32x4* wrow = (const f32x4*)(&wls[ck][0]);
#pragma unroll
        for (int o4 = 0; o4 < 16; o4++) {
            f32x4 w4 = wrow[o4];
            acc[o4 * 4 + 0] += xs * w4[0];
            acc[o4 * 4 + 1] += xs * w4[1];
            acc[o4 * 4 + 2] += xs * w4[2];
            acc[o4 * 4 + 3] += xs * w4[3];
        }
    }
    bf16x8 ob[8];
#pragma unroll
    for (int i = 0; i < 8; i++)
#pragma unroll
        for (int e = 0; e < 8; e++)
            ob[i][e] = (bf16)fmaxf(acc[i * 8 + e], 0.0f);
    bf16x8* dst = (bf16x8*)(out + (size_t)p * 64);
#pragma unroll
    for (int i = 0; i < 8; i++) dst[i] = ob[i];
}

// ---------------------------------------------------------------------------
// Pipelined gathered GEMM, scaled register blocking.
// Block tile BO outputs x BP positions, 4 waves arranged WO x WP; each wave
// computes (BO/WO)x(BP/WP) via acc[TO][TP] of 16x16 tiles -> 4x fragment
// reuse (16 ds_read_b128 per 32 MFMA at TO=TP=4). Triple-buffered async
// global_load_lds staging, bare s_barrier + counted vmcnt (never 0) so
// prefetch stays in flight across barriers. XOR-swizzled 16B segments for
// bank-conflict-free ds_read_b128.
// ---------------------------------------------------------------------------
template<int C, int BP, int BO, int WO, int WP>
__global__ __launch_bounds__(256) void conv_p(
    const bf16* __restrict__ in, const bf16* __restrict__ w,
    const float* __restrict__ bias, const int* __restrict__ table,
    bf16* __restrict__ out, float* __restrict__ slab,
    int N, int O, int S, int PO)
{
    constexpr int CH = C / 64;            // 64-ch chunks per k
    constexpr int CHUNKS = CH * 10;
    constexpr int CK = C * 10;
    constexpr int TO = (BO / WO) / 16;    // o-tiles per wave
    constexpr int TP = (BP / WP) / 16;    // p-tiles per wave
    constexpr int XI = BP / 32;           // X gload issues per wave per stage
    constexpr int WI = BO / 32;           // W gload issues per wave per stage
    constexpr int LPS = XI + WI;          // loads per stage per wave
    static_assert(LPS == 8 || LPS == 6, "vmcnt literal");

    __shared__ bf16 Xs[3][BP][64];        // [buf][row(pos)][64ch], swizzled segs
    __shared__ bf16 Ws[3][BO][64];        // [buf][row(o)][64ch]
    __shared__ int rowoff[BP][10];

    const int tid = threadIdx.x;
    const int lane = tid & 63;
    const int wid = tid >> 6;
    const int wo = wid & (WO - 1), wp = wid / WO;
    const int l16 = lane & 15, q = lane >> 4;

    const int p0 = blockIdx.x * BP;
    const int o0 = blockIdx.y * BO;
    const int z = blockIdx.z;

    for (int j = tid; j < BP * 10; j += 256) {
        int pp = j / 10, k = j - pp * 10;
        int p = p0 + pp;
        int b = p >= N;
        int n = p - b * N;
        rowoff[pp][k] = (b * N + table[n * 10 + k]) * C;
    }
    __syncthreads();

    // staging geometry: wave stages X rows [wid*BP/4, +BP/4) and W rows
    // [wid*BO/4, +BO/4), 8 rows (1KB) per issue. LDS stays linear; the
    // global source address is pre-swizzled: seg s of row r <- global seg
    // s^(r&7).
    int xsrow[XI], xgseg[XI];
#pragma unroll
    for (int t = 0; t < XI; t++) {
        int row = wid * (BP / 4) + t * 8 + (lane >> 3);
        xsrow[t] = row;
        xgseg[t] = (lane & 7) ^ (row & 7);
    }
    int wsrow[WI];
    const bf16* wbase[WI];
#pragma unroll
    for (int t = 0; t < WI; t++) {
        int row = wid * (BO / 4) + t * 8 + (lane >> 3);
        int gs = (lane & 7) ^ (row & 7);
        wsrow[t] = row;
        wbase[t] = w + (size_t)(o0 + row) * CK + gs * 8;
    }

    const int per = CHUNKS / S;
    const int c0chunk = z * per;

    auto stage = [&](int chunk, int b3) {
        int k = chunk / CH;
        int cofs = (chunk & (CH - 1)) * 64;
#pragma unroll
        for (int t = 0; t < XI; t++) {
            int ro = rowoff[xsrow[t]][k];
            gload_lds16(in + ro + cofs + xgseg[t] * 8,
                        &Xs[b3][wid * (BP / 4) + t * 8][0]);
        }
#pragma unroll
        for (int t = 0; t < WI; t++)
            gload_lds16(wbase[t] + chunk * 64,
                        &Ws[b3][wid * (BO / 4) + t * 8][0]);
    };

    f32x4 acc[TO][TP];
#pragma unroll
    for (int a = 0; a < TO; a++)
#pragma unroll
        for (int c = 0; c < TP; c++) acc[a][c] = (f32x4){0.f, 0.f, 0.f, 0.f};

    stage(c0chunk, 0);
    stage(c0chunk + 1, 1);

    const int obase = wo * (BO / WO);
    const int pbase = wp * (BP / WP);
    const int arow = obase + l16;
    const int brow = pbase + l16;
    const int sx = l16 & 7;

    int bi = 0, bs = 2;                   // compute buf, stage buf
    for (int i = 0; i < per; i++) {
        if constexpr (LPS == 8)
            asm volatile("s_waitcnt vmcnt(8)" ::: "memory");
        else
            asm volatile("s_waitcnt vmcnt(6)" ::: "memory");
        __builtin_amdgcn_s_barrier();
        const bf16* xb = &Xs[bi][0][0];
        const bf16* wb = &Ws[bi][0][0];
#pragma unroll
        for (int ks = 0; ks < 2; ks++) {
            int slot = ((ks * 4 + q) ^ sx) * 8;
            bf16x8 af[TO], bfr[TP];
#pragma unroll
            for (int to = 0; to < TO; to++)
                af[to] = *(const bf16x8*)(wb + (arow + to * 16) * 64 + slot);
#pragma unroll
            for (int tp = 0; tp < TP; tp++)
                bfr[tp] = *(const bf16x8*)(xb + (brow + tp * 16) * 64 + slot);
#pragma unroll
            for (int to = 0; to < TO; to++)
#pragma unroll
                for (int tp = 0; tp < TP; tp++)
                    acc[to][tp] = __builtin_amdgcn_mfma_f32_16x16x32_bf16(
                        af[to], bfr[tp], acc[to][tp], 0, 0, 0);
        }
        int nx = i + 2 < per ? i + 2 : per - 1;
        stage(c0chunk + nx, bs);
        bi = bi == 2 ? 0 : bi + 1;
        bs = bs == 2 ? 0 : bs + 1;
    }

    if (S == 1) {
#pragma unroll
        for (int to = 0; to < TO; ++to) {
            int ob = o0 + obase + to * 16 + q * 4;
            f32x4 bv = *(const f32x4*)(bias + ob);
#pragma unroll
            for (int tp = 0; tp < TP; ++tp) {
                int p = p0 + pbase + tp * 16 + l16;
                union { ushort4 u4; unsigned short s[4]; } pk;
#pragma unroll
                for (int r = 0; r < 4; r++) {
                    float v = fmaxf(acc[to][tp][r] + bv[r], 0.0f);
                    union { bf16 h; unsigned short u; } cc;
                    cc.h = (bf16)v;
                    pk.s[r] = cc.u;
                }
                *(ushort4*)(out + (size_t)p * O + ob) = pk.u4;
            }
        }
    } else {
        float* sb = slab + (size_t)z * PO;
#pragma unroll
        for (int to = 0; to < TO; ++to) {
            int ob = o0 + obase + to * 16 + q * 4;
#pragma unroll
            for (int tp = 0; tp < TP; ++tp) {
                int p = p0 + pbase + tp * 16 + l16;
                *(f32x4*)(sb + (size_t)p * O + ob) = acc[to][tp];
            }
        }
    }
}

// reduce S slabs + bias + relu -> bf16
__global__ __launch_bounds__(256) void epi_reduce(
    const float* __restrict__ slab, const float* __restrict__ bias,
    bf16* __restrict__ out, int PO, int Omask, int S)
{
    int t4 = (blockIdx.x * 256 + threadIdx.x) * 4;
    if (t4 >= PO) return;
    f32x4 s = *(const f32x4*)(slab + t4);
    for (int zz = 1; zz < S; zz++)
        s += *(const f32x4*)(slab + (size_t)zz * PO + t4);
    int o = t4 & Omask;
    f32x4 bv = *(const f32x4*)(bias + o);
    union { ushort4 u4; unsigned short e[4]; } pk;
#pragma unroll
    for (int r = 0; r < 4; r++) {
        float v = fmaxf(s[r] + bv[r], 0.0f);
        union { bf16 h; unsigned short u; } cc;
        cc.h = (bf16)v;
        pk.e[r] = cc.u;
    }
    *(ushort4*)((unsigned short*)out + t4) = pk.u4;
}

// ---------------------------------------------------------------------------
// Maxpool (bf16 post-ReLU: unsigned-short compare == float compare)
// ---------------------------------------------------------------------------
__global__ __launch_bounds__(256) void pool_kernel(
    const bf16* __restrict__ in, const int* __restrict__ adj,
    const int* __restrict__ pool, bf16* __restrict__ out,
    int N, int M, int c8shift)
{
    int t = blockIdx.x * 256 + threadIdx.x;
    int total = M << c8shift;
    if (t >= total) return;
    int cc = t & ((1 << c8shift) - 1);
    int j = t >> c8shift;
    int b = blockIdx.y;
    int C = 8 << c8shift;
    int s = pool[j];
    const int* a = adj + s * 4;
    const unsigned short* inu = (const unsigned short*)in;
    size_t base = (size_t)b * N * C + (size_t)cc * 8;
    u16x8 m = *(const u16x8*)(inu + base + (size_t)a[0] * C);
#pragma unroll
    for (int i = 1; i < 4; i++) {
        u16x8 v = *(const u16x8*)(inu + base + (size_t)a[i] * C);
#pragma unroll
        for (int e = 0; e < 8; e++) m[e] = v[e] > m[e] ? v[e] : m[e];
    }
    *(u16x8*)((unsigned short*)out + ((size_t)b * M + j) * C + (size_t)cc * 8) = m;
}

// Final pool: in [2][320][512] bf16 -> out (2,512,80) fp32
__global__ __launch_bounds__(256) void final_pool(
    const bf16* __restrict__ in, const int* __restrict__ adj,
    const int* __restrict__ pool, float* __restrict__ out)
{
    int t = blockIdx.x * 256 + threadIdx.x;
    if (t >= 81920) return;
    int j = t % 80;
    int rest = t / 80;
    int c = rest & 511;
    int b = rest >> 9;
    int s = pool[j];
    const int* a = adj + s * 4;
    float m = 0.0f;
#pragma unroll
    for (int i = 0; i < 4; i++) {
        float v = (float)in[((size_t)b * 320 + a[i]) * 512 + c];
        m = fmaxf(m, v);
    }
    out[t] = m;
}

// ---------------------------------------------------------------------------
extern "C" void kernel_launch(void* const* d_in, const int* in_sizes, int n_in,
                              void* d_out, int out_size, void* d_ws, size_t ws_size,
                              hipStream_t stream)
{
    const float* x = (const float*)d_in[0];
    const int* convT[5]; const int* adjT[5]; const int* poolT[5];
    for (int l = 0; l < 5; l++) {
        convT[l] = (const int*)d_in[1 + 3 * l];
        adjT[l]  = (const int*)d_in[2 + 3 * l];
        poolT[l] = (const int*)d_in[3 + 3 * l];
    }
    const float* W[13]; const float* Bs[13];
    for (int i = 0; i < 13; i++) {
        W[i]  = (const float*)d_in[16 + 2 * i];
        Bs[i] = (const float*)d_in[17 + 2 * i];
    }

    // ws = 256MB (observed fill size). Generous non-overlapping layout:
    bf16* wbf   = (bf16*)d_ws;                                // 32.7MB weights
    bf16* A     = (bf16*)((char*)d_ws + (40u << 20));         // 21MB activations
    bf16* Bb    = (bf16*)((char*)d_ws + (70u << 20));         // 21MB activations
    float* slabA = (float*)((char*)d_ws + (100u << 20));      // split-K slabs
    float* slabB = (float*)((char*)d_ws + (130u << 20));

    static const int woff[13] = {0, 0, 40960, 122880, 286720, 614400, 1269760,
                                 1925120, 3235840, 5857280, 8478720, 11100160, 13721600};

    prep_w<<<dim3(817152 / 256), dim3(256), 0, stream>>>(
        W[1], W[2], W[3], W[4], W[5], W[6], W[7], W[8], W[9], W[10], W[11], W[12], wbf);

    conv0_kernel<<<dim3(640), dim3(256), 0, stream>>>(x, W[0], Bs[0], convT[0], A);

    const int PO3 = 2560 * 512;
    const int PO4 = 640 * 512;

    // level 0  (O=64: BP=128,BO=64, waves 1x4)
    conv_p<64, 128, 64, 1, 4><<<dim3(1280, 1, 1), dim3(256), 0, stream>>>(
        A, wbf + woff[1], Bs[1], convT[0], Bb, nullptr, 81920, 64, 1, 0);
    pool_kernel<<<dim3(640, 2), dim3(256), 0, stream>>>(Bb, adjT[0], poolT[0], A, 81920, 20480, 3);
    // level 1  (128x128 blocks, waves 2x2)
    conv_p<64, 128, 128, 2, 2><<<dim3(320, 1, 1), dim3(256), 0, stream>>>(
        A, wbf + woff[2], Bs[2], convT[1], Bb, nullptr, 20480, 128, 1, 0);
    conv_p<128, 128, 128, 2, 2><<<dim3(320, 1, 1), dim3(256), 0, stream>>>(
        Bb, wbf + woff[3], Bs[3], convT[1], A, nullptr, 20480, 128, 1, 0);
    pool_kernel<<<dim3(320, 2), dim3(256), 0, stream>>>(A, adjT[1], poolT[1], Bb, 20480, 5120, 4);
    // level 2
    conv_p<128, 128, 128, 2, 2><<<dim3(80, 2, 1), dim3(256), 0, stream>>>(
        Bb, wbf + woff[4], Bs[4], convT[2], A, nullptr, 5120, 256, 1, 0);
    conv_p<256, 128, 128, 2, 2><<<dim3(80, 2, 1), dim3(256), 0, stream>>>(
        A, wbf + woff[5], Bs[5], convT[2], Bb, nullptr, 5120, 256, 1, 0);
    conv_p<256, 128, 128, 2, 2><<<dim3(80, 2, 1), dim3(256), 0, stream>>>(
        Bb, wbf + woff[6], Bs[6], convT[2], A, nullptr, 5120, 256, 1, 0);
    pool_kernel<<<dim3(160, 2), dim3(256), 0, stream>>>(A, adjT[2], poolT[2], Bb, 5120, 1280, 5);
    // level 3 (split-K S=2)
    conv_p<256, 128, 128, 2, 2><<<dim3(20, 4, 2), dim3(256), 0, stream>>>(
        Bb, wbf + woff[7], Bs[7], convT[3], nullptr, slabA, 1280, 512, 2, PO3);
    epi_reduce<<<dim3(PO3 / 1024), dim3(256), 0, stream>>>(slabA, Bs[7], A, PO3, 511, 2);
    conv_p<512, 128, 128, 2, 2><<<dim3(20, 4, 2), dim3(256), 0, stream>>>(
        A, wbf + woff[8], Bs[8], convT[3], nullptr, slabB, 1280, 512, 2, PO3);
    epi_reduce<<<dim3(PO3 / 1024), dim3(256), 0, stream>>>(slabB, Bs[8], Bb, PO3, 511, 2);
    conv_p<512, 128, 128, 2, 2><<<dim3(20, 4, 2), dim3(256), 0, stream>>>(
        Bb, wbf + woff[9], Bs[9], convT[3], nullptr, slabA, 1280, 512, 2, PO3);
    epi_reduce<<<dim3(PO3 / 1024), dim3(256), 0, stream>>>(slabA, Bs[9], A, PO3, 511, 2);
    pool_kernel<<<dim3(80, 2), dim3(256), 0, stream>>>(A, adjT[3], poolT[3], Bb, 1280, 320, 6);
    // level 4 (split-K S=8)
    conv_p<512, 128, 128, 2, 2><<<dim3(5, 4, 8), dim3(256), 0, stream>>>(
        Bb, wbf + woff[10], Bs[10], convT[4], nullptr, slabA, 320, 512, 8, PO4);
    epi_reduce<<<dim3(PO4 / 1024), dim3(256), 0, stream>>>(slabA, Bs[10], A, PO4, 511, 8);
    conv_p<512, 128, 128, 2, 2><<<dim3(5, 4, 8), dim3(256), 0, stream>>>(
        A, wbf + woff[11], Bs[11], convT[4], nullptr, slabB, 320, 512, 8, PO4);
    epi_reduce<<<dim3(PO4 / 1024), dim3(256), 0, stream>>>(slabB, Bs[11], Bb, PO4, 511, 8);
    conv_p<512, 128, 128, 2, 2><<<dim3(5, 4, 8), dim3(256), 0, stream>>>(
        Bb, wbf + woff[12], Bs[12], convT[4], nullptr, slabA, 320, 512, 8, PO4);
    epi_reduce<<<dim3(PO4 / 1024), dim3(256), 0, stream>>>(slabA, Bs[12], A, PO4, 511, 8);

    final_pool<<<dim3(320), dim3(256), 0, stream>>>(A, adjT[4], poolT[4], (float*)d_out);
}

// Round 4
// 595.150 us; speedup vs baseline: 1.0483x; 1.0483x over previous
//
#include <hip/hip_runtime.h>
#include <stdint.h>

typedef __bf16 bf16;
typedef bf16 bf16x8 __attribute__((ext_vector_type(8)));
typedef float f32x4 __attribute__((ext_vector_type(4)));
typedef unsigned short u16x8 __attribute__((ext_vector_type(8)));

__device__ __forceinline__ void gload_lds16(const bf16* g, bf16* l) {
    __builtin_amdgcn_global_load_lds(
        (const __attribute__((address_space(1))) void*)g,
        (__attribute__((address_space(3))) void*)l, 16, 0, 0);
}

// ---------------------------------------------------------------------------
// Prep: convert+transpose weights w1..w12 from fp32 (O,C,K) to bf16 [O][K*C]
// (r = k*C + c ordering). Coalesced: thread owns one (o, c-pair); 5x float4
// contiguous loads, register transpose, ushort2-packed stores at k*C stride.
// ---------------------------------------------------------------------------
template<int C>
__device__ __forceinline__ void cvt_pair(const float* __restrict__ src,
                                         bf16* __restrict__ dst,
                                         int tp, int base5)
{
    int ocp = tp - base5;          // pair index; oc = 2*ocp
    int oc  = ocp * 2;             // = o*C + c  (c even)
    int o   = oc / C;              // C is power of 2 -> shift
    int c   = oc & (C - 1);
    const f32x4* s4 = (const f32x4*)(src + (size_t)oc * 10);  // 80B-aligned
    float v[20];                   // v[0..9] = channel c, v[10..19] = c+1
#pragma unroll
    for (int j = 0; j < 5; j++) {
        f32x4 p = s4[j];
#pragma unroll
        for (int e = 0; e < 4; e++) v[4 * j + e] = p[e];
    }
    unsigned short* d = (unsigned short*)(dst + (size_t)base5 * 20
                                              + (size_t)o * 10 * C + c);
#pragma unroll
    for (int k = 0; k < 10; k++) {
        union { bf16 h; unsigned short u; } a, b;
        a.h = (bf16)v[k];
        b.h = (bf16)v[10 + k];
        uint32_t pk = (uint32_t)a.u | ((uint32_t)b.u << 16);
        *(uint32_t*)(d + (size_t)k * C) = pk;
    }
}

__global__ __launch_bounds__(256) void prep_w(
    const float* w1, const float* w2, const float* w3, const float* w4,
    const float* w5, const float* w6, const float* w7, const float* w8,
    const float* w9, const float* w10, const float* w11, const float* w12,
    bf16* __restrict__ dst)
{
    int t = blockIdx.x * 256 + threadIdx.x;   // pair index, total 817152
    if (t >= 817152) return;
    if      (t <   2048) cvt_pair< 64>(w1,  dst, t, 0);
    else if (t <   6144) cvt_pair< 64>(w2,  dst, t, 2048);
    else if (t <  14336) cvt_pair<128>(w3,  dst, t, 6144);
    else if (t <  30720) cvt_pair<128>(w4,  dst, t, 14336);
    else if (t <  63488) cvt_pair<256>(w5,  dst, t, 30720);
    else if (t <  96256) cvt_pair<256>(w6,  dst, t, 63488);
    else if (t < 161792) cvt_pair<256>(w7,  dst, t, 96256);
    else if (t < 292864) cvt_pair<512>(w8,  dst, t, 161792);
    else if (t < 423936) cvt_pair<512>(w9,  dst, t, 292864);
    else if (t < 555008) cvt_pair<512>(w10, dst, t, 423936);
    else if (t < 686080) cvt_pair<512>(w11, dst, t, 555008);
    else                 cvt_pair<512>(w12, dst, t, 686080);
}

// ---------------------------------------------------------------------------
// conv0: C=3, K=10, O=64, fp32 VALU. out: [2][81920][64] bf16
// ---------------------------------------------------------------------------
__global__ __launch_bounds__(256) void conv0_kernel(
    const float* __restrict__ x, const float* __restrict__ w0,
    const float* __restrict__ b0, const int* __restrict__ table,
    bf16* __restrict__ out)
{
    const int N = 81920;
    __shared__ float wls[30][64];
    __shared__ float bls[64];
    int tid = threadIdx.x;
    for (int i = tid; i < 1920; i += 256) {
        int o = i / 30, ck = i - o * 30;
        wls[ck][o] = w0[i];
    }
    if (tid < 64) bls[tid] = b0[tid];
    __syncthreads();

    int p = blockIdx.x * 256 + tid;
    int b = p >= N;
    int n = p - b * N;
    int idx[10];
    const int* trow = table + n * 10;
#pragma unroll
    for (int k = 0; k < 10; k++) idx[k] = trow[k];
    float xv[30];
#pragma unroll
    for (int c = 0; c < 3; c++)
#pragma unroll
        for (int k = 0; k < 10; k++)
            xv[c * 10 + k] = x[(b * 3 + c) * N + idx[k]];

    float acc[64];
#pragma unroll
    for (int o = 0; o < 64; o++) acc[o] = bls[o];
    for (int ck = 0; ck < 30; ck++) {
        float xs = xv[ck];
        const f32x4* wrow = (const f32x4*)(&wls[ck][0]);
#pragma unroll
        for (int o4 = 0; o4 < 16; o4++) {
            f32x4 w4 = wrow[o4];
            acc[o4 * 4 + 0] += xs * w4[0];
            acc[o4 * 4 + 1] += xs * w4[1];
            acc[o4 * 4 + 2] += xs * w4[2];
            acc[o4 * 4 + 3] += xs * w4[3];
        }
    }
    bf16x8 ob[8];
#pragma unroll
    for (int i = 0; i < 8; i++)
#pragma unroll
        for (int e = 0; e < 8; e++)
            ob[i][e] = (bf16)fmaxf(acc[i * 8 + e], 0.0f);
    bf16x8* dst = (bf16x8*)(out + (size_t)p * 64);
#pragma unroll
    for (int i = 0; i < 8; i++) dst[i] = ob[i];
}

// ---------------------------------------------------------------------------
// Pipelined gathered GEMM, 64x64-per-wave register blocking (16 ds_read_b128
// per 32 MFMA), DOUBLE-buffered async global_load_lds staging so LDS stays
// <= 70.7KB -> 2 blocks/CU co-residency. Two bare s_barriers per K-iter
// (2nd guards the re-stage write-after-read); counted vmcnt (never 0) keeps
// the next chunk's loads in flight across both barriers. XOR-swizzled 16B
// segments for bank-conflict-free ds_read_b128.
// ---------------------------------------------------------------------------
template<int C, int BP, int BO, int WO, int WP>
__global__ __launch_bounds__(256) void conv_p(
    const bf16* __restrict__ in, const bf16* __restrict__ w,
    const float* __restrict__ bias, const int* __restrict__ table,
    bf16* __restrict__ out, float* __restrict__ slab,
    int N, int O, int S, int PO)
{
    constexpr int CH = C / 64;            // 64-ch chunks per k
    constexpr int CHUNKS = CH * 10;
    constexpr int CK = C * 10;
    constexpr int TO = (BO / WO) / 16;    // o-tiles per wave
    constexpr int TP = (BP / WP) / 16;    // p-tiles per wave
    constexpr int XI = BP / 32;           // X gload issues per wave per stage
    constexpr int WI = BO / 32;           // W gload issues per wave per stage
    constexpr int LPS = XI + WI;          // loads per stage per wave
    static_assert(LPS == 8 || LPS == 6, "vmcnt literal");

    __shared__ bf16 Xs[2][BP][64];        // [buf][row(pos)][64ch], swizzled segs
    __shared__ bf16 Ws[2][BO][64];        // [buf][row(o)][64ch]
    __shared__ int rowoff[BP][10];

    const int tid = threadIdx.x;
    const int lane = tid & 63;
    const int wid = tid >> 6;
    const int wo = wid & (WO - 1), wp = wid / WO;
    const int l16 = lane & 15, q = lane >> 4;

    const int p0 = blockIdx.x * BP;
    const int o0 = blockIdx.y * BO;
    const int z = blockIdx.z;

    for (int j = tid; j < BP * 10; j += 256) {
        int pp = j / 10, k = j - pp * 10;
        int p = p0 + pp;
        int b = p >= N;
        int n = p - b * N;
        rowoff[pp][k] = (b * N + table[n * 10 + k]) * C;
    }
    __syncthreads();

    // staging geometry: wave stages X rows [wid*BP/4, +BP/4) and W rows
    // [wid*BO/4, +BO/4), 8 rows (1KB) per issue. LDS stays linear; the
    // global source is pre-swizzled: LDS seg s of row r <- global seg s^(r&7).
    int xsrow[XI], xgseg[XI];
#pragma unroll
    for (int t = 0; t < XI; t++) {
        int row = wid * (BP / 4) + t * 8 + (lane >> 3);
        xsrow[t] = row;
        xgseg[t] = (lane & 7) ^ (row & 7);
    }
    const bf16* wbase[WI];
#pragma unroll
    for (int t = 0; t < WI; t++) {
        int row = wid * (BO / 4) + t * 8 + (lane >> 3);
        int gs = (lane & 7) ^ (row & 7);
        wbase[t] = w + (size_t)(o0 + row) * CK + gs * 8;
    }

    const int per = CHUNKS / S;
    const int c0chunk = z * per;

    auto stage = [&](int chunk, int b2) {
        int k = chunk / CH;
        int cofs = (chunk & (CH - 1)) * 64;
#pragma unroll
        for (int t = 0; t < XI; t++) {
            int ro = rowoff[xsrow[t]][k];
            gload_lds16(in + ro + cofs + xgseg[t] * 8,
                        &Xs[b2][wid * (BP / 4) + t * 8][0]);
        }
#pragma unroll
        for (int t = 0; t < WI; t++)
            gload_lds16(wbase[t] + chunk * 64,
                        &Ws[b2][wid * (BO / 4) + t * 8][0]);
    };

    f32x4 acc[TO][TP];
#pragma unroll
    for (int a = 0; a < TO; a++)
#pragma unroll
        for (int c = 0; c < TP; c++) acc[a][c] = (f32x4){0.f, 0.f, 0.f, 0.f};

    stage(c0chunk, 0);
    stage(c0chunk + 1, 1);

    const int obase = wo * (BO / WO);
    const int pbase = wp * (BP / WP);
    const int arow = obase + l16;
    const int brow = pbase + l16;
    const int sx = l16 & 7;

    for (int i = 0; i < per; i++) {
        const int bi = i & 1;
        // wait: stage(i) landed; stage(i+1)'s LPS loads may stay in flight
        if constexpr (LPS == 8)
            asm volatile("s_waitcnt vmcnt(8)" ::: "memory");
        else
            asm volatile("s_waitcnt vmcnt(6)" ::: "memory");
        __builtin_amdgcn_s_barrier();
        const bf16* xb = &Xs[bi][0][0];
        const bf16* wb = &Ws[bi][0][0];
#pragma unroll
        for (int ks = 0; ks < 2; ks++) {
            int slot = ((ks * 4 + q) ^ sx) * 8;
            bf16x8 af[TO], bfr[TP];
#pragma unroll
            for (int to = 0; to < TO; to++)
                af[to] = *(const bf16x8*)(wb + (arow + to * 16) * 64 + slot);
#pragma unroll
            for (int tp = 0; tp < TP; tp++)
                bfr[tp] = *(const bf16x8*)(xb + (brow + tp * 16) * 64 + slot);
#pragma unroll
            for (int to = 0; to < TO; to++)
#pragma unroll
                for (int tp = 0; tp < TP; tp++)
                    acc[to][tp] = __builtin_amdgcn_mfma_f32_16x16x32_bf16(
                        af[to], bfr[tp], acc[to][tp], 0, 0, 0);
        }
        // all waves done reading buf bi (their ds_reads drained by MFMA deps)
        __builtin_amdgcn_s_barrier();
        if (i + 2 < per) stage(c0chunk + i + 2, bi);
    }

    if (S == 1) {
#pragma unroll
        for (int to = 0; to < TO; ++to) {
            int ob = o0 + obase + to * 16 + q * 4;
            f32x4 bv = *(const f32x4*)(bias + ob);
#pragma unroll
            for (int tp = 0; tp < TP; ++tp) {
                int p = p0 + pbase + tp * 16 + l16;
                union { ushort4 u4; unsigned short s[4]; } pk;
#pragma unroll
                for (int r = 0; r < 4; r++) {
                    float v = fmaxf(acc[to][tp][r] + bv[r], 0.0f);
                    union { bf16 h; unsigned short u; } cc;
                    cc.h = (bf16)v;
                    pk.s[r] = cc.u;
                }
                *(ushort4*)(out + (size_t)p * O + ob) = pk.u4;
            }
        }
    } else {
        float* sb = slab + (size_t)z * PO;
#pragma unroll
        for (int to = 0; to < TO; ++to) {
            int ob = o0 + obase + to * 16 + q * 4;
#pragma unroll
            for (int tp = 0; tp < TP; ++tp) {
                int p = p0 + pbase + tp * 16 + l16;
                *(f32x4*)(sb + (size_t)p * O + ob) = acc[to][tp];
            }
        }
    }
}

// reduce S slabs + bias + relu -> bf16
__global__ __launch_bounds__(256) void epi_reduce(
    const float* __restrict__ slab, const float* __restrict__ bias,
    bf16* __restrict__ out, int PO, int Omask, int S)
{
    int t4 = (blockIdx.x * 256 + threadIdx.x) * 4;
    if (t4 >= PO) return;
    f32x4 s = *(const f32x4*)(slab + t4);
    for (int zz = 1; zz < S; zz++)
        s += *(const f32x4*)(slab + (size_t)zz * PO + t4);
    int o = t4 & Omask;
    f32x4 bv = *(const f32x4*)(bias + o);
    union { ushort4 u4; unsigned short e[4]; } pk;
#pragma unroll
    for (int r = 0; r < 4; r++) {
        float v = fmaxf(s[r] + bv[r], 0.0f);
        union { bf16 h; unsigned short u; } cc;
        cc.h = (bf16)v;
        pk.e[r] = cc.u;
    }
    *(ushort4*)((unsigned short*)out + t4) = pk.u4;
}

// ---------------------------------------------------------------------------
// Maxpool (bf16 post-ReLU: unsigned-short compare == float compare)
// ---------------------------------------------------------------------------
__global__ __launch_bounds__(256) void pool_kernel(
    const bf16* __restrict__ in, const int* __restrict__ adj,
    const int* __restrict__ pool, bf16* __restrict__ out,
    int N, int M, int c8shift)
{
    int t = blockIdx.x * 256 + threadIdx.x;
    int total = M << c8shift;
    if (t >= total) return;
    int cc = t & ((1 << c8shift) - 1);
    int j = t >> c8shift;
    int b = blockIdx.y;
    int C = 8 << c8shift;
    int s = pool[j];
    const int* a = adj + s * 4;
    const unsigned short* inu = (const unsigned short*)in;
    size_t base = (size_t)b * N * C + (size_t)cc * 8;
    u16x8 m = *(const u16x8*)(inu + base + (size_t)a[0] * C);
#pragma unroll
    for (int i = 1; i < 4; i++) {
        u16x8 v = *(const u16x8*)(inu + base + (size_t)a[i] * C);
#pragma unroll
        for (int e = 0; e < 8; e++) m[e] = v[e] > m[e] ? v[e] : m[e];
    }
    *(u16x8*)((unsigned short*)out + ((size_t)b * M + j) * C + (size_t)cc * 8) = m;
}

// Final pool: in [2][320][512] bf16 -> out (2,512,80) fp32
__global__ __launch_bounds__(256) void final_pool(
    const bf16* __restrict__ in, const int* __restrict__ adj,
    const int* __restrict__ pool, float* __restrict__ out)
{
    int t = blockIdx.x * 256 + threadIdx.x;
    if (t >= 81920) return;
    int j = t % 80;
    int rest = t / 80;
    int c = rest & 511;
    int b = rest >> 9;
    int s = pool[j];
    const int* a = adj + s * 4;
    float m = 0.0f;
#pragma unroll
    for (int i = 0; i < 4; i++) {
        float v = (float)in[((size_t)b * 320 + a[i]) * 512 + c];
        m = fmaxf(m, v);
    }
    out[t] = m;
}

// ---------------------------------------------------------------------------
extern "C" void kernel_launch(void* const* d_in, const int* in_sizes, int n_in,
                              void* d_out, int out_size, void* d_ws, size_t ws_size,
                              hipStream_t stream)
{
    const float* x = (const float*)d_in[0];
    const int* convT[5]; const int* adjT[5]; const int* poolT[5];
    for (int l = 0; l < 5; l++) {
        convT[l] = (const int*)d_in[1 + 3 * l];
        adjT[l]  = (const int*)d_in[2 + 3 * l];
        poolT[l] = (const int*)d_in[3 + 3 * l];
    }
    const float* W[13]; const float* Bs[13];
    for (int i = 0; i < 13; i++) {
        W[i]  = (const float*)d_in[16 + 2 * i];
        Bs[i] = (const float*)d_in[17 + 2 * i];
    }

    // ws = 256MB. Non-overlapping layout:
    bf16* wbf   = (bf16*)d_ws;                                // 32.7MB weights
    bf16* A     = (bf16*)((char*)d_ws + (40u << 20));         // 21MB activations
    bf16* Bb    = (bf16*)((char*)d_ws + (70u << 20));         // 21MB activations
    float* slabA = (float*)((char*)d_ws + (100u << 20));      // 21MB split-K slabs
    float* slabB = (float*)((char*)d_ws + (130u << 20));      // 21MB

    static const int woff[13] = {0, 0, 40960, 122880, 286720, 614400, 1269760,
                                 1925120, 3235840, 5857280, 8478720, 11100160, 13721600};

    prep_w<<<dim3(817152 / 256), dim3(256), 0, stream>>>(
        W[1], W[2], W[3], W[4], W[5], W[6], W[7], W[8], W[9], W[10], W[11], W[12], wbf);

    conv0_kernel<<<dim3(640), dim3(256), 0, stream>>>(x, W[0], Bs[0], convT[0], A);

    const int PO2 = 10240 * 256;   // level-2 split-K slab stride (fp32 elems)
    const int PO3 = 2560 * 512;
    const int PO4 = 640 * 512;

    // level 0  (O=64: BP=128,BO=64, waves 1x4, LDS 54KB -> 3 blocks/CU)
    conv_p<64, 128, 64, 1, 4><<<dim3(1280, 1, 1), dim3(256), 0, stream>>>(
        A, wbf + woff[1], Bs[1], convT[0], Bb, nullptr, 81920, 64, 1, 0);
    pool_kernel<<<dim3(640, 2), dim3(256), 0, stream>>>(Bb, adjT[0], poolT[0], A, 81920, 20480, 3);
    // level 1  (128x128, 2x2 waves, LDS 70.7KB -> 2 blocks/CU; grids 320)
    conv_p<64, 128, 128, 2, 2><<<dim3(320, 1, 1), dim3(256), 0, stream>>>(
        A, wbf + woff[2], Bs[2], convT[1], Bb, nullptr, 20480, 128, 1, 0);
    conv_p<128, 128, 128, 2, 2><<<dim3(320, 1, 1), dim3(256), 0, stream>>>(
        Bb, wbf + woff[3], Bs[3], convT[1], A, nullptr, 20480, 128, 1, 0);
    pool_kernel<<<dim3(320, 2), dim3(256), 0, stream>>>(A, adjT[1], poolT[1], Bb, 20480, 5120, 4);
    // level 2 (split-K S=2 -> 320 blocks)
    conv_p<128, 128, 128, 2, 2><<<dim3(80, 2, 2), dim3(256), 0, stream>>>(
        Bb, wbf + woff[4], Bs[4], convT[2], nullptr, slabA, 5120, 256, 2, PO2);
    epi_reduce<<<dim3(PO2 / 1024), dim3(256), 0, stream>>>(slabA, Bs[4], A, PO2, 255, 2);
    conv_p<256, 128, 128, 2, 2><<<dim3(80, 2, 2), dim3(256), 0, stream>>>(
        A, wbf + woff[5], Bs[5], convT[2], nullptr, slabB, 5120, 256, 2, PO2);
    epi_reduce<<<dim3(PO2 / 1024), dim3(256), 0, stream>>>(slabB, Bs[5], Bb, PO2, 255, 2);
    conv_p<256, 128, 128, 2, 2><<<dim3(80, 2, 2), dim3(256), 0, stream>>>(
        Bb, wbf + woff[6], Bs[6], convT[2], nullptr, slabA, 5120, 256, 2, PO2);
    epi_reduce<<<dim3(PO2 / 1024), dim3(256), 0, stream>>>(slabA, Bs[6], A, PO2, 255, 2);
    pool_kernel<<<dim3(160, 2), dim3(256), 0, stream>>>(A, adjT[2], poolT[2], Bb, 5120, 1280, 5);
    // level 3 (split-K S=4 -> 320 blocks)
    conv_p<256, 128, 128, 2, 2><<<dim3(20, 4, 4), dim3(256), 0, stream>>>(
        Bb, wbf + woff[7], Bs[7], convT[3], nullptr, slabB, 1280, 512, 4, PO3);
    epi_reduce<<<dim3(PO3 / 1024), dim3(256), 0, stream>>>(slabB, Bs[7], A, PO3, 511, 4);
    conv_p<512, 128, 128, 2, 2><<<dim3(20, 4, 4), dim3(256), 0, stream>>>(
        A, wbf + woff[8], Bs[8], convT[3], nullptr, slabA, 1280, 512, 4, PO3);
    epi_reduce<<<dim3(PO3 / 1024), dim3(256), 0, stream>>>(slabA, Bs[8], Bb, PO3, 511, 4);
    conv_p<512, 128, 128, 2, 2><<<dim3(20, 4, 4), dim3(256), 0, stream>>>(
        Bb, wbf + woff[9], Bs[9], convT[3], nullptr, slabB, 1280, 512, 4, PO3);
    epi_reduce<<<dim3(PO3 / 1024), dim3(256), 0, stream>>>(slabB, Bs[9], A, PO3, 511, 4);
    pool_kernel<<<dim3(80, 2), dim3(256), 0, stream>>>(A, adjT[3], poolT[3], Bb, 1280, 320, 6);
    // level 4 (split-K S=16 -> 320 blocks, per=5)
    conv_p<512, 128, 128, 2, 2><<<dim3(5, 4, 16), dim3(256), 0, stream>>>(
        Bb, wbf + woff[10], Bs[10], convT[4], nullptr, slabA, 320, 512, 16, PO4);
    epi_reduce<<<dim3(PO4 / 1024), dim3(256), 0, stream>>>(slabA, Bs[10], A, PO4, 511, 16);
    conv_p<512, 128, 128, 2, 2><<<dim3(5, 4, 16), dim3(256), 0, stream>>>(
        A, wbf + woff[11], Bs[11], convT[4], nullptr, slabB, 320, 512, 16, PO4);
    epi_reduce<<<dim3(PO4 / 1024), dim3(256), 0, stream>>>(slabB, Bs[11], Bb, PO4, 511, 16);
    conv_p<512, 128, 128, 2, 2><<<dim3(5, 4, 16), dim3(256), 0, stream>>>(
        Bb, wbf + woff[12], Bs[12], convT[4], nullptr, slabA, 320, 512, 16, PO4);
    epi_reduce<<<dim3(PO4 / 1024), dim3(256), 0, stream>>>(slabA, Bs[12], A, PO4, 511, 16);

    final_pool<<<dim3(320), dim3(256), 0, stream>>>(A, adjT[4], poolT[4], (float*)d_out);
}

// Round 6
// 559.386 us; speedup vs baseline: 1.1153x; 1.0639x over previous
//
#include <hip/hip_runtime.h>
#include <stdint.h>

typedef __bf16 bf16;
typedef bf16 bf16x8 __attribute__((ext_vector_type(8)));
typedef float f32x4 __attribute__((ext_vector_type(4)));
typedef unsigned short u16x8 __attribute__((ext_vector_type(8)));

__device__ __forceinline__ void gload_lds16(const bf16* g, bf16* l) {
    __builtin_amdgcn_global_load_lds(
        (const __attribute__((address_space(1))) void*)g,
        (__attribute__((address_space(3))) void*)l, 16, 0, 0);
}

// ---------------------------------------------------------------------------
// Prep: convert+transpose weights w1..w12 from fp32 (O,C,K) to bf16 [O][K*C]
// (r = k*C + c ordering). Coalesced: thread owns one (o, c-pair); 5x float4
// contiguous loads, register transpose, ushort2-packed stores at k*C stride.
// ---------------------------------------------------------------------------
template<int C>
__device__ __forceinline__ void cvt_pair(const float* __restrict__ src,
                                         bf16* __restrict__ dst,
                                         int tp, int base5)
{
    int ocp = tp - base5;          // pair index; oc = 2*ocp
    int oc  = ocp * 2;             // = o*C + c  (c even)
    int o   = oc / C;              // C is power of 2 -> shift
    int c   = oc & (C - 1);
    const f32x4* s4 = (const f32x4*)(src + (size_t)oc * 10);  // 80B-aligned
    float v[20];                   // v[0..9] = channel c, v[10..19] = c+1
#pragma unroll
    for (int j = 0; j < 5; j++) {
        f32x4 p = s4[j];
#pragma unroll
        for (int e = 0; e < 4; e++) v[4 * j + e] = p[e];
    }
    unsigned short* d = (unsigned short*)(dst + (size_t)base5 * 20
                                              + (size_t)o * 10 * C + c);
#pragma unroll
    for (int k = 0; k < 10; k++) {
        union { bf16 h; unsigned short u; } a, b;
        a.h = (bf16)v[k];
        b.h = (bf16)v[10 + k];
        uint32_t pk = (uint32_t)a.u | ((uint32_t)b.u << 16);
        *(uint32_t*)(d + (size_t)k * C) = pk;
    }
}

__global__ __launch_bounds__(256) void prep_w(
    const float* w1, const float* w2, const float* w3, const float* w4,
    const float* w5, const float* w6, const float* w7, const float* w8,
    const float* w9, const float* w10, const float* w11, const float* w12,
    bf16* __restrict__ dst)
{
    int t = blockIdx.x * 256 + threadIdx.x;   // pair index, total 817152
    if (t >= 817152) return;
    if      (t <   2048) cvt_pair< 64>(w1,  dst, t, 0);
    else if (t <   6144) cvt_pair< 64>(w2,  dst, t, 2048);
    else if (t <  14336) cvt_pair<128>(w3,  dst, t, 6144);
    else if (t <  30720) cvt_pair<128>(w4,  dst, t, 14336);
    else if (t <  63488) cvt_pair<256>(w5,  dst, t, 30720);
    else if (t <  96256) cvt_pair<256>(w6,  dst, t, 63488);
    else if (t < 161792) cvt_pair<256>(w7,  dst, t, 96256);
    else if (t < 292864) cvt_pair<512>(w8,  dst, t, 161792);
    else if (t < 423936) cvt_pair<512>(w9,  dst, t, 292864);
    else if (t < 555008) cvt_pair<512>(w10, dst, t, 423936);
    else if (t < 686080) cvt_pair<512>(w11, dst, t, 555008);
    else                 cvt_pair<512>(w12, dst, t, 686080);
}

// ---------------------------------------------------------------------------
// conv0: C=3, K=10, O=64, fp32 VALU. out: [2][81920][64] bf16
// ---------------------------------------------------------------------------
__global__ __launch_bounds__(256) void conv0_kernel(
    const float* __restrict__ x, const float* __restrict__ w0,
    const float* __restrict__ b0, const int* __restrict__ table,
    bf16* __restrict__ out)
{
    const int N = 81920;
    __shared__ float wls[30][64];
    __shared__ float bls[64];
    int tid = threadIdx.x;
    for (int i = tid; i < 1920; i += 256) {
        int o = i / 30, ck = i - o * 30;
        wls[ck][o] = w0[i];
    }
    if (tid < 64) bls[tid] = b0[tid];
    __syncthreads();

    int p = blockIdx.x * 256 + tid;
    int b = p >= N;
    int n = p - b * N;
    int idx[10];
    const int* trow = table + n * 10;
#pragma unroll
    for (int k = 0; k < 10; k++) idx[k] = trow[k];
    float xv[30];
#pragma unroll
    for (int c = 0; c < 3; c++)
#pragma unroll
        for (int k = 0; k < 10; k++)
            xv[c * 10 + k] = x[(b * 3 + c) * N + idx[k]];

    float acc[64];
#pragma unroll
    for (int o = 0; o < 64; o++) acc[o] = bls[o];
    for (int ck = 0; ck < 30; ck++) {
        float xs = xv[ck];
        const f32x4* wrow = (const f32x4*)(&wls[ck][0]);
#pragma unroll
        for (int o4 = 0; o4 < 16; o4++) {
            f32x4 w4 = wrow[o4];
            acc[o4 * 4 + 0] += xs * w4[0];
            acc[o4 * 4 + 1] += xs * w4[1];
            acc[o4 * 4 + 2] += xs * w4[2];
            acc[o4 * 4 + 3] += xs * w4[3];
        }
    }
    bf16x8 ob[8];
#pragma unroll
    for (int i = 0; i < 8; i++)
#pragma unroll
        for (int e = 0; e < 8; e++)
            ob[i][e] = (bf16)fmaxf(acc[i * 8 + e], 0.0f);
    bf16x8* dst = (bf16x8*)(out + (size_t)p * 64);
#pragma unroll
    for (int i = 0; i < 8; i++) dst[i] = ob[i];
}

// ---------------------------------------------------------------------------
// conv_reg64: level-0 conv (C=64, O=64) — register-direct, ZERO LDS, ZERO
// barriers. MFMA fragment layout (lane row = l&15, k-elem = (l>>4)*8+e) is
// loaded directly from global as per-lane 16B bf16x8 loads: X gather lands
// straight in B-fragments, W (80KB, L2-hot) straight in A-fragments. Waves
// progress independently — no convoy. Per wave: 64 outputs x 32 positions,
// acc[4][2], 10-chunk K-loop with named double-buffered fragment sets.
// ---------------------------------------------------------------------------
struct Frags64 {
    bf16x8 a[4][2];   // [o-tile][k-slice]
    bf16x8 b[2][2];   // [p-tile][k-slice]
};

__global__ __launch_bounds__(256) void conv_reg64(
    const bf16* __restrict__ in, const bf16* __restrict__ w,
    const float* __restrict__ bias, const int* __restrict__ table,
    bf16* __restrict__ out, int N)
{
    const int tid = threadIdx.x;
    const int lane = tid & 63;
    const int wid = tid >> 6;
    const int l16 = lane & 15, q = lane >> 4;

    const int p0 = blockIdx.x * 128 + wid * 32;   // wave's first position

    // per-lane gathered-row element offsets: 2 positions x 10 k
    int nrow[2][10];
#pragma unroll
    for (int tp = 0; tp < 2; tp++) {
        int p = p0 + tp * 16 + l16;
        int b = p >= N;
        int n = p - b * N;
        const int* tr = table + n * 10;
#pragma unroll
        for (int k = 0; k < 10; k++)
            nrow[tp][k] = (b * N + tr[k]) * 64;
    }

    const bf16* wbase[4];
#pragma unroll
    for (int to = 0; to < 4; to++)
        wbase[to] = w + (to * 16 + l16) * 640 + q * 8;
    const bf16* xq = in + q * 8;

    f32x4 acc[4][2];
#pragma unroll
    for (int a = 0; a < 4; a++)
#pragma unroll
        for (int c = 0; c < 2; c++) acc[a][c] = (f32x4){0.f, 0.f, 0.f, 0.f};

    auto loadF = [&](int k, Frags64& F) {
#pragma unroll
        for (int to = 0; to < 4; to++)
#pragma unroll
            for (int ks = 0; ks < 2; ks++)
                F.a[to][ks] = *(const bf16x8*)(wbase[to] + k * 64 + ks * 32);
#pragma unroll
        for (int tp = 0; tp < 2; tp++)
#pragma unroll
            for (int ks = 0; ks < 2; ks++)
                F.b[tp][ks] = *(const bf16x8*)(xq + nrow[tp][k] + ks * 32);
    };
    auto mm = [&](Frags64& F) {
#pragma unroll
        for (int ks = 0; ks < 2; ks++)
#pragma unroll
            for (int to = 0; to < 4; to++)
#pragma unroll
                for (int tp = 0; tp < 2; tp++)
                    acc[to][tp] = __builtin_amdgcn_mfma_f32_16x16x32_bf16(
                        F.a[to][ks], F.b[tp][ks], acc[to][tp], 0, 0, 0);
    };

    Frags64 F0, F1;
    loadF(0, F0);
#pragma unroll
    for (int k = 0; k < 10; k += 2) {
        loadF(k + 1, F1);
        mm(F0);
        if (k + 2 < 10) loadF(k + 2, F0);
        mm(F1);
    }

#pragma unroll
    for (int to = 0; to < 4; ++to) {
        int ob = to * 16 + q * 4;
        f32x4 bv = *(const f32x4*)(bias + ob);
#pragma unroll
        for (int tp = 0; tp < 2; ++tp) {
            int p = p0 + tp * 16 + l16;
            union { ushort4 u4; unsigned short s[4]; } pk;
#pragma unroll
            for (int r = 0; r < 4; r++) {
                float v = fmaxf(acc[to][tp][r] + bv[r], 0.0f);
                union { bf16 h; unsigned short u; } cc;
                cc.h = (bf16)v;
                pk.s[r] = cc.u;
            }
            *(ushort4*)(out + (size_t)p * 64 + ob) = pk.u4;
        }
    }
}

// ---------------------------------------------------------------------------
// Pipelined gathered GEMM (round-2 proven structure): triple-buffered async
// global_load_lds staging, bare s_barrier + counted vmcnt(4) (never 0) so
// prefetch stays in flight across the barrier. 64x64 block, 2x2 waves,
// XOR-swizzled 16B segments for bank-conflict-free ds_read_b128.
// ---------------------------------------------------------------------------
template<int C, int BP, int BO, int WO, int WP>
__global__ __launch_bounds__(256) void conv_p(
    const bf16* __restrict__ in, const bf16* __restrict__ w,
    const float* __restrict__ bias, const int* __restrict__ table,
    bf16* __restrict__ out, float* __restrict__ slab,
    int N, int O, int S, int PO)
{
    constexpr int CH = C / 64;            // 64-ch chunks per k
    constexpr int CHUNKS = CH * 10;
    constexpr int CK = C * 10;
    constexpr int TO = (BO / WO) / 16;    // o-tiles per wave
    constexpr int TP = (BP / WP) / 16;    // p-tiles per wave
    constexpr int XI = BP / 32;           // X gload issues per wave per stage
    constexpr int WI = BO / 32;           // W gload issues per wave per stage
    constexpr int LPS = XI + WI;          // loads per stage per wave
    static_assert(LPS == 4, "vmcnt literal assumes 4 loads/stage");

    __shared__ bf16 Xs[3][BP][64];        // [buf][row(pos)][64ch], swizzled segs
    __shared__ bf16 Ws[3][BO][64];        // [buf][row(o)][64ch]
    __shared__ int rowoff[BP][10];

    const int tid = threadIdx.x;
    const int lane = tid & 63;
    const int wid = tid >> 6;
    const int wo = wid & (WO - 1), wp = wid / WO;
    const int l16 = lane & 15, q = lane >> 4;

    const int p0 = blockIdx.x * BP;
    const int o0 = blockIdx.y * BO;
    const int z = blockIdx.z;

    for (int j = tid; j < BP * 10; j += 256) {
        int pp = j / 10, k = j - pp * 10;
        int p = p0 + pp;
        int b = p >= N;
        int n = p - b * N;
        rowoff[pp][k] = (b * N + table[n * 10 + k]) * C;
    }
    __syncthreads();

    // staging geometry: wave stages X rows [wid*BP/4,+BP/4), W rows
    // [wid*BO/4,+BO/4), 8 rows (1KB) per issue. LDS linear; global source
    // pre-swizzled: LDS seg s of row r <- global seg s^(r&7).
    int xsrow[XI], xgseg[XI];
#pragma unroll
    for (int t = 0; t < XI; t++) {
        int row = wid * (BP / 4) + t * 8 + (lane >> 3);
        xsrow[t] = row;
        xgseg[t] = (lane & 7) ^ (row & 7);
    }
    const bf16* wbase[WI];
#pragma unroll
    for (int t = 0; t < WI; t++) {
        int row = wid * (BO / 4) + t * 8 + (lane >> 3);
        int gs = (lane & 7) ^ (row & 7);
        wbase[t] = w + (size_t)(o0 + row) * CK + gs * 8;
    }

    const int per = CHUNKS / S;
    const int c0chunk = z * per;

    auto stage = [&](int chunk, int b3) {
        int k = chunk / CH;
        int cofs = (chunk & (CH - 1)) * 64;
#pragma unroll
        for (int t = 0; t < XI; t++) {
            int ro = rowoff[xsrow[t]][k];
            gload_lds16(in + ro + cofs + xgseg[t] * 8,
                        &Xs[b3][wid * (BP / 4) + t * 8][0]);
        }
#pragma unroll
        for (int t = 0; t < WI; t++)
            gload_lds16(wbase[t] + chunk * 64,
                        &Ws[b3][wid * (BO / 4) + t * 8][0]);
    };

    f32x4 acc[TO][TP];
#pragma unroll
    for (int a = 0; a < TO; a++)
#pragma unroll
        for (int c = 0; c < TP; c++) acc[a][c] = (f32x4){0.f, 0.f, 0.f, 0.f};

    stage(c0chunk, 0);
    stage(c0chunk + 1, 1);

    const int obase = wo * (BO / WO);
    const int pbase = wp * (BP / WP);
    const int arow = obase + l16;
    const int brow = pbase + l16;
    const int sx = l16 & 7;

    int bi = 0, bs = 2;                   // compute buf, stage buf
    for (int i = 0; i < per; i++) {
        asm volatile("s_waitcnt vmcnt(4)" ::: "memory");
        __builtin_amdgcn_s_barrier();
        const bf16* xb = &Xs[bi][0][0];
        const bf16* wb = &Ws[bi][0][0];
#pragma unroll
        for (int ks = 0; ks < 2; ks++) {
            int slot = ((ks * 4 + q) ^ sx) * 8;
            bf16x8 af[TO], bfr[TP];
#pragma unroll
            for (int to = 0; to < TO; to++)
                af[to] = *(const bf16x8*)(wb + (arow + to * 16) * 64 + slot);
#pragma unroll
            for (int tp = 0; tp < TP; tp++)
                bfr[tp] = *(const bf16x8*)(xb + (brow + tp * 16) * 64 + slot);
#pragma unroll
            for (int to = 0; to < TO; to++)
#pragma unroll
                for (int tp = 0; tp < TP; tp++)
                    acc[to][tp] = __builtin_amdgcn_mfma_f32_16x16x32_bf16(
                        af[to], bfr[tp], acc[to][tp], 0, 0, 0);
        }
        int nx = i + 2 < per ? i + 2 : per - 1;
        stage(c0chunk + nx, bs);
        bi = bi == 2 ? 0 : bi + 1;
        bs = bs == 2 ? 0 : bs + 1;
    }

    if (S == 1) {
#pragma unroll
        for (int to = 0; to < TO; ++to) {
            int ob = o0 + obase + to * 16 + q * 4;
            f32x4 bv = *(const f32x4*)(bias + ob);
#pragma unroll
            for (int tp = 0; tp < TP; ++tp) {
                int p = p0 + pbase + tp * 16 + l16;
                union { ushort4 u4; unsigned short s[4]; } pk;
#pragma unroll
                for (int r = 0; r < 4; r++) {
                    float v = fmaxf(acc[to][tp][r] + bv[r], 0.0f);
                    union { bf16 h; unsigned short u; } cc;
                    cc.h = (bf16)v;
                    pk.s[r] = cc.u;
                }
                *(ushort4*)(out + (size_t)p * O + ob) = pk.u4;
            }
        }
    } else {
        float* sb = slab + (size_t)z * PO;
#pragma unroll
        for (int to = 0; to < TO; ++to) {
            int ob = o0 + obase + to * 16 + q * 4;
#pragma unroll
            for (int tp = 0; tp < TP; ++tp) {
                int p = p0 + pbase + tp * 16 + l16;
                *(f32x4*)(sb + (size_t)p * O + ob) = acc[to][tp];
            }
        }
    }
}

// reduce S slabs + bias + relu -> bf16
__global__ __launch_bounds__(256) void epi_reduce(
    const float* __restrict__ slab, const float* __restrict__ bias,
    bf16* __restrict__ out, int PO, int Omask, int S)
{
    int t4 = (blockIdx.x * 256 + threadIdx.x) * 4;
    if (t4 >= PO) return;
    f32x4 s = *(const f32x4*)(slab + t4);
    for (int zz = 1; zz < S; zz++)
        s += *(const f32x4*)(slab + (size_t)zz * PO + t4);
    int o = t4 & Omask;
    f32x4 bv = *(const f32x4*)(bias + o);
    union { ushort4 u4; unsigned short e[4]; } pk;
#pragma unroll
    for (int r = 0; r < 4; r++) {
        float v = fmaxf(s[r] + bv[r], 0.0f);
        union { bf16 h; unsigned short u; } cc;
        cc.h = (bf16)v;
        pk.e[r] = cc.u;
    }
    *(ushort4*)((unsigned short*)out + t4) = pk.u4;
}

// ---------------------------------------------------------------------------
// Maxpool (bf16 post-ReLU: unsigned-short compare == float compare)
// ---------------------------------------------------------------------------
__global__ __launch_bounds__(256) void pool_kernel(
    const bf16* __restrict__ in, const int* __restrict__ adj,
    const int* __restrict__ pool, bf16* __restrict__ out,
    int N, int M, int c8shift)
{
    int t = blockIdx.x * 256 + threadIdx.x;
    int total = M << c8shift;
    if (t >= total) return;
    int cc = t & ((1 << c8shift) - 1);
    int j = t >> c8shift;
    int b = blockIdx.y;
    int C = 8 << c8shift;
    int s = pool[j];
    const int* a = adj + s * 4;
    const unsigned short* inu = (const unsigned short*)in;
    size_t base = (size_t)b * N * C + (size_t)cc * 8;
    u16x8 m = *(const u16x8*)(inu + base + (size_t)a[0] * C);
#pragma unroll
    for (int i = 1; i < 4; i++) {
        u16x8 v = *(const u16x8*)(inu + base + (size_t)a[i] * C);
#pragma unroll
        for (int e = 0; e < 8; e++) m[e] = v[e] > m[e] ? v[e] : m[e];
    }
    *(u16x8*)((unsigned short*)out + ((size_t)b * M + j) * C + (size_t)cc * 8) = m;
}

// Final pool: in [2][320][512] bf16 -> out (2,512,80) fp32
__global__ __launch_bounds__(256) void final_pool(
    const bf16* __restrict__ in, const int* __restrict__ adj,
    const int* __restrict__ pool, float* __restrict__ out)
{
    int t = blockIdx.x * 256 + threadIdx.x;
    if (t >= 81920) return;
    int j = t % 80;
    int rest = t / 80;
    int c = rest & 511;
    int b = rest >> 9;
    int s = pool[j];
    const int* a = adj + s * 4;
    float m = 0.0f;
#pragma unroll
    for (int i = 0; i < 4; i++) {
        float v = (float)in[((size_t)b * 320 + a[i]) * 512 + c];
        m = fmaxf(m, v);
    }
    out[t] = m;
}

// ---------------------------------------------------------------------------
extern "C" void kernel_launch(void* const* d_in, const int* in_sizes, int n_in,
                              void* d_out, int out_size, void* d_ws, size_t ws_size,
                              hipStream_t stream)
{
    const float* x = (const float*)d_in[0];
    const int* convT[5]; const int* adjT[5]; const int* poolT[5];
    for (int l = 0; l < 5; l++) {
        convT[l] = (const int*)d_in[1 + 3 * l];
        adjT[l]  = (const int*)d_in[2 + 3 * l];
        poolT[l] = (const int*)d_in[3 + 3 * l];
    }
    const float* W[13]; const float* Bs[13];
    for (int i = 0; i < 13; i++) {
        W[i]  = (const float*)d_in[16 + 2 * i];
        Bs[i] = (const float*)d_in[17 + 2 * i];
    }

    // ws = 256MB. Non-overlapping layout:
    bf16* wbf   = (bf16*)d_ws;                                // 32.7MB weights
    bf16* A     = (bf16*)((char*)d_ws + (40u << 20));         // 21MB activations
    bf16* Bb    = (bf16*)((char*)d_ws + (70u << 20));         // 21MB activations
    float* slabA = (float*)((char*)d_ws + (100u << 20));      // split-K slabs
    float* slabB = (float*)((char*)d_ws + (130u << 20));

    static const int woff[13] = {0, 0, 40960, 122880, 286720, 614400, 1269760,
                                 1925120, 3235840, 5857280, 8478720, 11100160, 13721600};

    prep_w<<<dim3(817152 / 256), dim3(256), 0, stream>>>(
        W[1], W[2], W[3], W[4], W[5], W[6], W[7], W[8], W[9], W[10], W[11], W[12], wbf);

    conv0_kernel<<<dim3(640), dim3(256), 0, stream>>>(x, W[0], Bs[0], convT[0], A);

    const int PO3 = 2560 * 512;
    const int PO4 = 640 * 512;

    // level 0: register-direct conv (zero LDS / zero barriers)
    conv_reg64<<<dim3(1280), dim3(256), 0, stream>>>(
        A, wbf + woff[1], Bs[1], convT[0], Bb, 81920);
    pool_kernel<<<dim3(640, 2), dim3(256), 0, stream>>>(Bb, adjT[0], poolT[0], A, 81920, 20480, 3);
    // level 1  (grid.x = 640: 640*64 = 40960 = 2*N positions)
    conv_p<64, 64, 64, 2, 2><<<dim3(640, 2, 1), dim3(256), 0, stream>>>(
        A, wbf + woff[2], Bs[2], convT[1], Bb, nullptr, 20480, 128, 1, 0);
    conv_p<128, 64, 64, 2, 2><<<dim3(640, 2, 1), dim3(256), 0, stream>>>(
        Bb, wbf + woff[3], Bs[3], convT[1], A, nullptr, 20480, 128, 1, 0);
    pool_kernel<<<dim3(320, 2), dim3(256), 0, stream>>>(A, adjT[1], poolT[1], Bb, 20480, 5120, 4);
    // level 2
    conv_p<128, 64, 64, 2, 2><<<dim3(160, 4, 1), dim3(256), 0, stream>>>(
        Bb, wbf + woff[4], Bs[4], convT[2], A, nullptr, 5120, 256, 1, 0);
    conv_p<256, 64, 64, 2, 2><<<dim3(160, 4, 1), dim3(256), 0, stream>>>(
        A, wbf + woff[5], Bs[5], convT[2], Bb, nullptr, 5120, 256, 1, 0);
    conv_p<256, 64, 64, 2, 2><<<dim3(160, 4, 1), dim3(256), 0, stream>>>(
        Bb, wbf + woff[6], Bs[6], convT[2], A, nullptr, 5120, 256, 1, 0);
    pool_kernel<<<dim3(160, 2), dim3(256), 0, stream>>>(A, adjT[2], poolT[2], Bb, 5120, 1280, 5);
    // level 3 (split-K S=2 -> 640 blocks)
    conv_p<256, 64, 64, 2, 2><<<dim3(40, 8, 2), dim3(256), 0, stream>>>(
        Bb, wbf + woff[7], Bs[7], convT[3], nullptr, slabA, 1280, 512, 2, PO3);
    epi_reduce<<<dim3(PO3 / 1024), dim3(256), 0, stream>>>(slabA, Bs[7], A, PO3, 511, 2);
    conv_p<512, 64, 64, 2, 2><<<dim3(40, 8, 2), dim3(256), 0, stream>>>(
        A, wbf + woff[8], Bs[8], convT[3], nullptr, slabB, 1280, 512, 2, PO3);
    epi_reduce<<<dim3(PO3 / 1024), dim3(256), 0, stream>>>(slabB, Bs[8], Bb, PO3, 511, 2);
    conv_p<512, 64, 64, 2, 2><<<dim3(40, 8, 2), dim3(256), 0, stream>>>(
        Bb, wbf + woff[9], Bs[9], convT[3], nullptr, slabA, 1280, 512, 2, PO3);
    epi_reduce<<<dim3(PO3 / 1024), dim3(256), 0, stream>>>(slabA, Bs[9], A, PO3, 511, 2);
    pool_kernel<<<dim3(80, 2), dim3(256), 0, stream>>>(A, adjT[3], poolT[3], Bb, 1280, 320, 6);
    // level 4 (split-K S=8 -> 640 blocks)
    conv_p<512, 64, 64, 2, 2><<<dim3(10, 8, 8), dim3(256), 0, stream>>>(
        Bb, wbf + woff[10], Bs[10], convT[4], nullptr, slabA, 320, 512, 8, PO4);
    epi_reduce<<<dim3(PO4 / 1024), dim3(256), 0, stream>>>(slabA, Bs[10], A, PO4, 511, 8);
    conv_p<512, 64, 64, 2, 2><<<dim3(10, 8, 8), dim3(256), 0, stream>>>(
        A, wbf + woff[11], Bs[11], convT[4], nullptr, slabB, 320, 512, 8, PO4);
    epi_reduce<<<dim3(PO4 / 1024), dim3(256), 0, stream>>>(slabB, Bs[11], Bb, PO4, 511, 8);
    conv_p<512, 64, 64, 2, 2><<<dim3(10, 8, 8), dim3(256), 0, stream>>>(
        Bb, wbf + woff[12], Bs[12], convT[4], nullptr, slabA, 320, 512, 8, PO4);
    epi_reduce<<<dim3(PO4 / 1024), dim3(256), 0, stream>>>(slabA, Bs[12], A, PO4, 511, 8);

    final_pool<<<dim3(320), dim3(256), 0, stream>>>(A, adjT[4], poolT[4], (float*)d_out);
}

// Round 7
// 522.020 us; speedup vs baseline: 1.1952x; 1.0716x over previous
//
#include <hip/hip_runtime.h>
#include <stdint.h>

typedef __bf16 bf16;
typedef bf16 bf16x8 __attribute__((ext_vector_type(8)));
typedef float f32x4 __attribute__((ext_vector_type(4)));
typedef unsigned short u16x8 __attribute__((ext_vector_type(8)));

__device__ __forceinline__ void gload_lds16(const bf16* g, bf16* l) {
    __builtin_amdgcn_global_load_lds(
        (const __attribute__((address_space(1))) void*)g,
        (__attribute__((address_space(3))) void*)l, 16, 0, 0);
}

// ---------------------------------------------------------------------------
// Prep: convert+transpose weights w1..w12 from fp32 (O,C,K) to bf16 [O][K*C]
// (r = k*C + c ordering). Coalesced: thread owns one (o, c-pair); 5x float4
// contiguous loads, register transpose, ushort2-packed stores at k*C stride.
// ---------------------------------------------------------------------------
template<int C>
__device__ __forceinline__ void cvt_pair(const float* __restrict__ src,
                                         bf16* __restrict__ dst,
                                         int tp, int base5)
{
    int ocp = tp - base5;          // pair index; oc = 2*ocp
    int oc  = ocp * 2;             // = o*C + c  (c even)
    int o   = oc / C;              // C is power of 2 -> shift
    int c   = oc & (C - 1);
    const f32x4* s4 = (const f32x4*)(src + (size_t)oc * 10);  // 80B-aligned
    float v[20];                   // v[0..9] = channel c, v[10..19] = c+1
#pragma unroll
    for (int j = 0; j < 5; j++) {
        f32x4 p = s4[j];
#pragma unroll
        for (int e = 0; e < 4; e++) v[4 * j + e] = p[e];
    }
    unsigned short* d = (unsigned short*)(dst + (size_t)base5 * 20
                                              + (size_t)o * 10 * C + c);
#pragma unroll
    for (int k = 0; k < 10; k++) {
        union { bf16 h; unsigned short u; } a, b;
        a.h = (bf16)v[k];
        b.h = (bf16)v[10 + k];
        uint32_t pk = (uint32_t)a.u | ((uint32_t)b.u << 16);
        *(uint32_t*)(d + (size_t)k * C) = pk;
    }
}

__global__ __launch_bounds__(256) void prep_w(
    const float* w1, const float* w2, const float* w3, const float* w4,
    const float* w5, const float* w6, const float* w7, const float* w8,
    const float* w9, const float* w10, const float* w11, const float* w12,
    bf16* __restrict__ dst)
{
    int t = blockIdx.x * 256 + threadIdx.x;   // pair index, total 817152
    if (t >= 817152) return;
    if      (t <   2048) cvt_pair< 64>(w1,  dst, t, 0);
    else if (t <   6144) cvt_pair< 64>(w2,  dst, t, 2048);
    else if (t <  14336) cvt_pair<128>(w3,  dst, t, 6144);
    else if (t <  30720) cvt_pair<128>(w4,  dst, t, 14336);
    else if (t <  63488) cvt_pair<256>(w5,  dst, t, 30720);
    else if (t <  96256) cvt_pair<256>(w6,  dst, t, 63488);
    else if (t < 161792) cvt_pair<256>(w7,  dst, t, 96256);
    else if (t < 292864) cvt_pair<512>(w8,  dst, t, 161792);
    else if (t < 423936) cvt_pair<512>(w9,  dst, t, 292864);
    else if (t < 555008) cvt_pair<512>(w10, dst, t, 423936);
    else if (t < 686080) cvt_pair<512>(w11, dst, t, 555008);
    else                 cvt_pair<512>(w12, dst, t, 686080);
}

// ---------------------------------------------------------------------------
// conv0: C=3, K=10, O=64, fp32 VALU. out: [2][81920][64] bf16
// ---------------------------------------------------------------------------
__global__ __launch_bounds__(256) void conv0_kernel(
    const float* __restrict__ x, const float* __restrict__ w0,
    const float* __restrict__ b0, const int* __restrict__ table,
    bf16* __restrict__ out)
{
    const int N = 81920;
    __shared__ float wls[30][64];
    __shared__ float bls[64];
    int tid = threadIdx.x;
    for (int i = tid; i < 1920; i += 256) {
        int o = i / 30, ck = i - o * 30;
        wls[ck][o] = w0[i];
    }
    if (tid < 64) bls[tid] = b0[tid];
    __syncthreads();

    int p = blockIdx.x * 256 + tid;
    int b = p >= N;
    int n = p - b * N;
    int idx[10];
    const int* trow = table + n * 10;
#pragma unroll
    for (int k = 0; k < 10; k++) idx[k] = trow[k];
    float xv[30];
#pragma unroll
    for (int c = 0; c < 3; c++)
#pragma unroll
        for (int k = 0; k < 10; k++)
            xv[c * 10 + k] = x[(b * 3 + c) * N + idx[k]];

    float acc[64];
#pragma unroll
    for (int o = 0; o < 64; o++) acc[o] = bls[o];
    for (int ck = 0; ck < 30; ck++) {
        float xs = xv[ck];
        const f32x4* wrow = (const f32x4*)(&wls[ck][0]);
#pragma unroll
        for (int o4 = 0; o4 < 16; o4++) {
            f32x4 w4 = wrow[o4];
            acc[o4 * 4 + 0] += xs * w4[0];
            acc[o4 * 4 + 1] += xs * w4[1];
            acc[o4 * 4 + 2] += xs * w4[2];
            acc[o4 * 4 + 3] += xs * w4[3];
        }
    }
    bf16x8 ob[8];
#pragma unroll
    for (int i = 0; i < 8; i++)
#pragma unroll
        for (int e = 0; e < 8; e++)
            ob[i][e] = (bf16)fmaxf(acc[i * 8 + e], 0.0f);
    bf16x8* dst = (bf16x8*)(out + (size_t)p * 64);
#pragma unroll
    for (int i = 0; i < 8; i++) dst[i] = ob[i];
}

// ---------------------------------------------------------------------------
// conv_reg64 v2: level-0 conv (C=64, O=64).
// W staged ONCE into LDS [10 chunks][64 rows][64ch] (80KB, XOR-seg-swizzled
// via pre-swizzled global_load_lds source) -> ONE barrier total, zero
// barriers in the K-loop. X (the random gather) loads per-lane direct from
// global into named B-fragment registers, 4-deep prefetch, fully unrolled
// 10-chunk schedule. __launch_bounds__(256,1) unlocks the VGPR budget so
// all 4 prefetch buffers stay live (round-6 failure: 68 VGPR serialized).
// 2 blocks/CU (LDS 80KB), 8 waves/CU. Per chunk/wave: 8 LDS b128 : 16 MFMA.
// ---------------------------------------------------------------------------
__global__ __launch_bounds__(256, 1) void conv_reg64(
    const bf16* __restrict__ in, const bf16* __restrict__ w,
    const float* __restrict__ bias, const int* __restrict__ table,
    bf16* __restrict__ out, int N)
{
    __shared__ bf16 Ws[10][64][64];   // [chunk][row][64ch], seg-swizzled

    const int tid = threadIdx.x;
    const int lane = tid & 63;
    const int wid = tid >> 6;
    const int l16 = lane & 15, q = lane >> 4;
    const int sx = l16 & 7;

    // ---- stage W once: 80 wave-issues (1KB each), 20 per wave ----
    {
        int lrow8 = lane >> 3;          // 0..7
        int lseg  = lane & 7;           // 0..7
#pragma unroll
        for (int t = 0; t < 20; t++) {
            int u = wid * 20 + t;       // 0..79
            int k = u >> 3;             // chunk 0..9
            int rb = u & 7;             // row-block 0..7
            int row = rb * 8 + lrow8;
            int gs = lseg ^ (row & 7);  // pre-swizzled global seg
            gload_lds16(w + (size_t)row * 640 + k * 64 + gs * 8,
                        &Ws[k][rb * 8][0]);
        }
    }

    const int p0 = blockIdx.x * 128 + wid * 32;   // wave's first position

    // per-lane gathered-row element offsets: 2 positions x 10 k
    int nrow[2][10];
#pragma unroll
    for (int tp = 0; tp < 2; tp++) {
        int p = p0 + tp * 16 + l16;
        int b = p >= N;
        int n = p - b * N;
        const int* tr = table + n * 10;
#pragma unroll
        for (int k = 0; k < 10; k++)
            nrow[tp][k] = (b * N + tr[k]) * 64;
    }
    const bf16* xq = in + q * 8;

    f32x4 acc[4][2];
#pragma unroll
    for (int a = 0; a < 4; a++)
#pragma unroll
        for (int c = 0; c < 2; c++) acc[a][c] = (f32x4){0.f, 0.f, 0.f, 0.f};

    auto loadX = [&](int k, bf16x8 (&B)[2][2]) {
#pragma unroll
        for (int tp = 0; tp < 2; tp++)
#pragma unroll
            for (int ks = 0; ks < 2; ks++)
                B[tp][ks] = *(const bf16x8*)(xq + nrow[tp][k] + ks * 32);
    };
    auto mmc = [&](int k, bf16x8 (&B)[2][2]) {
#pragma unroll
        for (int ks = 0; ks < 2; ks++) {
            bf16x8 af[4];
#pragma unroll
            for (int to = 0; to < 4; to++) {
                int row = to * 16 + l16;
                int s = (ks * 4 + q) ^ sx;
                af[to] = *(const bf16x8*)(&Ws[k][row][s * 8]);
            }
#pragma unroll
            for (int to = 0; to < 4; to++)
#pragma unroll
                for (int tp = 0; tp < 2; tp++)
                    acc[to][tp] = __builtin_amdgcn_mfma_f32_16x16x32_bf16(
                        af[to], B[tp][ks], acc[to][tp], 0, 0, 0);
        }
    };

    // 4-deep X prefetch (16 loads in flight), issued BEFORE the W drain so
    // they ride through the barrier.
    bf16x8 B0[2][2], B1[2][2], B2[2][2], B3[2][2];
    loadX(0, B0); loadX(1, B1); loadX(2, B2); loadX(3, B3);

    // drain the 20 W-stage loads (leave the 16 X loads in flight), then sync
    asm volatile("s_waitcnt vmcnt(16)" ::: "memory");
    __builtin_amdgcn_s_barrier();

    // fully unrolled 10-chunk schedule, prefetch distance 3-4 chunks
    mmc(0, B0); loadX(4, B0);
    mmc(1, B1); loadX(5, B1);
    mmc(2, B2); loadX(6, B2);
    mmc(3, B3); loadX(7, B3);
    mmc(4, B0); loadX(8, B0);
    mmc(5, B1); loadX(9, B1);
    mmc(6, B2);
    mmc(7, B3);
    mmc(8, B0);
    mmc(9, B1);

#pragma unroll
    for (int to = 0; to < 4; ++to) {
        int ob = to * 16 + q * 4;
        f32x4 bv = *(const f32x4*)(bias + ob);
#pragma unroll
        for (int tp = 0; tp < 2; ++tp) {
            int p = p0 + tp * 16 + l16;
            union { ushort4 u4; unsigned short s[4]; } pk;
#pragma unroll
            for (int r = 0; r < 4; r++) {
                float v = fmaxf(acc[to][tp][r] + bv[r], 0.0f);
                union { bf16 h; unsigned short u; } cc;
                cc.h = (bf16)v;
                pk.s[r] = cc.u;
            }
            *(ushort4*)(out + (size_t)p * 64 + ob) = pk.u4;
        }
    }
}

// ---------------------------------------------------------------------------
// Pipelined gathered GEMM (round-2 proven structure): triple-buffered async
// global_load_lds staging, bare s_barrier + counted vmcnt(4) (never 0) so
// prefetch stays in flight across the barrier. 64x64 block, 2x2 waves,
// XOR-swizzled 16B segments for bank-conflict-free ds_read_b128.
// ---------------------------------------------------------------------------
template<int C, int BP, int BO, int WO, int WP>
__global__ __launch_bounds__(256) void conv_p(
    const bf16* __restrict__ in, const bf16* __restrict__ w,
    const float* __restrict__ bias, const int* __restrict__ table,
    bf16* __restrict__ out, float* __restrict__ slab,
    int N, int O, int S, int PO)
{
    constexpr int CH = C / 64;            // 64-ch chunks per k
    constexpr int CHUNKS = CH * 10;
    constexpr int CK = C * 10;
    constexpr int TO = (BO / WO) / 16;    // o-tiles per wave
    constexpr int TP = (BP / WP) / 16;    // p-tiles per wave
    constexpr int XI = BP / 32;           // X gload issues per wave per stage
    constexpr int WI = BO / 32;           // W gload issues per wave per stage
    constexpr int LPS = XI + WI;          // loads per stage per wave
    static_assert(LPS == 4, "vmcnt literal assumes 4 loads/stage");

    __shared__ bf16 Xs[3][BP][64];        // [buf][row(pos)][64ch], swizzled segs
    __shared__ bf16 Ws[3][BO][64];        // [buf][row(o)][64ch]
    __shared__ int rowoff[BP][10];

    const int tid = threadIdx.x;
    const int lane = tid & 63;
    const int wid = tid >> 6;
    const int wo = wid & (WO - 1), wp = wid / WO;
    const int l16 = lane & 15, q = lane >> 4;

    const int p0 = blockIdx.x * BP;
    const int o0 = blockIdx.y * BO;
    const int z = blockIdx.z;

    for (int j = tid; j < BP * 10; j += 256) {
        int pp = j / 10, k = j - pp * 10;
        int p = p0 + pp;
        int b = p >= N;
        int n = p - b * N;
        rowoff[pp][k] = (b * N + table[n * 10 + k]) * C;
    }
    __syncthreads();

    int xsrow[XI], xgseg[XI];
#pragma unroll
    for (int t = 0; t < XI; t++) {
        int row = wid * (BP / 4) + t * 8 + (lane >> 3);
        xsrow[t] = row;
        xgseg[t] = (lane & 7) ^ (row & 7);
    }
    const bf16* wbase[WI];
#pragma unroll
    for (int t = 0; t < WI; t++) {
        int row = wid * (BO / 4) + t * 8 + (lane >> 3);
        int gs = (lane & 7) ^ (row & 7);
        wbase[t] = w + (size_t)(o0 + row) * CK + gs * 8;
    }

    const int per = CHUNKS / S;
    const int c0chunk = z * per;

    auto stage = [&](int chunk, int b3) {
        int k = chunk / CH;
        int cofs = (chunk & (CH - 1)) * 64;
#pragma unroll
        for (int t = 0; t < XI; t++) {
            int ro = rowoff[xsrow[t]][k];
            gload_lds16(in + ro + cofs + xgseg[t] * 8,
                        &Xs[b3][wid * (BP / 4) + t * 8][0]);
        }
#pragma unroll
        for (int t = 0; t < WI; t++)
            gload_lds16(wbase[t] + chunk * 64,
                        &Ws[b3][wid * (BO / 4) + t * 8][0]);
    };

    f32x4 acc[TO][TP];
#pragma unroll
    for (int a = 0; a < TO; a++)
#pragma unroll
        for (int c = 0; c < TP; c++) acc[a][c] = (f32x4){0.f, 0.f, 0.f, 0.f};

    stage(c0chunk, 0);
    stage(c0chunk + 1, 1);

    const int obase = wo * (BO / WO);
    const int pbase = wp * (BP / WP);
    const int arow = obase + l16;
    const int brow = pbase + l16;
    const int sx = l16 & 7;

    int bi = 0, bs = 2;                   // compute buf, stage buf
    for (int i = 0; i < per; i++) {
        asm volatile("s_waitcnt vmcnt(4)" ::: "memory");
        __builtin_amdgcn_s_barrier();
        const bf16* xb = &Xs[bi][0][0];
        const bf16* wb = &Ws[bi][0][0];
#pragma unroll
        for (int ks = 0; ks < 2; ks++) {
            int slot = ((ks * 4 + q) ^ sx) * 8;
            bf16x8 af[TO], bfr[TP];
#pragma unroll
            for (int to = 0; to < TO; to++)
                af[to] = *(const bf16x8*)(wb + (arow + to * 16) * 64 + slot);
#pragma unroll
            for (int tp = 0; tp < TP; tp++)
                bfr[tp] = *(const bf16x8*)(xb + (brow + tp * 16) * 64 + slot);
#pragma unroll
            for (int to = 0; to < TO; to++)
#pragma unroll
                for (int tp = 0; tp < TP; tp++)
                    acc[to][tp] = __builtin_amdgcn_mfma_f32_16x16x32_bf16(
                        af[to], bfr[tp], acc[to][tp], 0, 0, 0);
        }
        int nx = i + 2 < per ? i + 2 : per - 1;
        stage(c0chunk + nx, bs);
        bi = bi == 2 ? 0 : bi + 1;
        bs = bs == 2 ? 0 : bs + 1;
    }

    if (S == 1) {
#pragma unroll
        for (int to = 0; to < TO; ++to) {
            int ob = o0 + obase + to * 16 + q * 4;
            f32x4 bv = *(const f32x4*)(bias + ob);
#pragma unroll
            for (int tp = 0; tp < TP; ++tp) {
                int p = p0 + pbase + tp * 16 + l16;
                union { ushort4 u4; unsigned short s[4]; } pk;
#pragma unroll
                for (int r = 0; r < 4; r++) {
                    float v = fmaxf(acc[to][tp][r] + bv[r], 0.0f);
                    union { bf16 h; unsigned short u; } cc;
                    cc.h = (bf16)v;
                    pk.s[r] = cc.u;
                }
                *(ushort4*)(out + (size_t)p * O + ob) = pk.u4;
            }
        }
    } else {
        float* sb = slab + (size_t)z * PO;
#pragma unroll
        for (int to = 0; to < TO; ++to) {
            int ob = o0 + obase + to * 16 + q * 4;
#pragma unroll
            for (int tp = 0; tp < TP; ++tp) {
                int p = p0 + pbase + tp * 16 + l16;
                *(f32x4*)(sb + (size_t)p * O + ob) = acc[to][tp];
            }
        }
    }
}

// reduce S slabs + bias + relu -> bf16
__global__ __launch_bounds__(256) void epi_reduce(
    const float* __restrict__ slab, const float* __restrict__ bias,
    bf16* __restrict__ out, int PO, int Omask, int S)
{
    int t4 = (blockIdx.x * 256 + threadIdx.x) * 4;
    if (t4 >= PO) return;
    f32x4 s = *(const f32x4*)(slab + t4);
    for (int zz = 1; zz < S; zz++)
        s += *(const f32x4*)(slab + (size_t)zz * PO + t4);
    int o = t4 & Omask;
    f32x4 bv = *(const f32x4*)(bias + o);
    union { ushort4 u4; unsigned short e[4]; } pk;
#pragma unroll
    for (int r = 0; r < 4; r++) {
        float v = fmaxf(s[r] + bv[r], 0.0f);
        union { bf16 h; unsigned short u; } cc;
        cc.h = (bf16)v;
        pk.e[r] = cc.u;
    }
    *(ushort4*)((unsigned short*)out + t4) = pk.u4;
}

// ---------------------------------------------------------------------------
// Maxpool (bf16 post-ReLU: unsigned-short compare == float compare)
// ---------------------------------------------------------------------------
__global__ __launch_bounds__(256) void pool_kernel(
    const bf16* __restrict__ in, const int* __restrict__ adj,
    const int* __restrict__ pool, bf16* __restrict__ out,
    int N, int M, int c8shift)
{
    int t = blockIdx.x * 256 + threadIdx.x;
    int total = M << c8shift;
    if (t >= total) return;
    int cc = t & ((1 << c8shift) - 1);
    int j = t >> c8shift;
    int b = blockIdx.y;
    int C = 8 << c8shift;
    int s = pool[j];
    const int* a = adj + s * 4;
    const unsigned short* inu = (const unsigned short*)in;
    size_t base = (size_t)b * N * C + (size_t)cc * 8;
    u16x8 m = *(const u16x8*)(inu + base + (size_t)a[0] * C);
#pragma unroll
    for (int i = 1; i < 4; i++) {
        u16x8 v = *(const u16x8*)(inu + base + (size_t)a[i] * C);
#pragma unroll
        for (int e = 0; e < 8; e++) m[e] = v[e] > m[e] ? v[e] : m[e];
    }
    *(u16x8*)((unsigned short*)out + ((size_t)b * M + j) * C + (size_t)cc * 8) = m;
}

// Final pool: in [2][320][512] bf16 -> out (2,512,80) fp32
__global__ __launch_bounds__(256) void final_pool(
    const bf16* __restrict__ in, const int* __restrict__ adj,
    const int* __restrict__ pool, float* __restrict__ out)
{
    int t = blockIdx.x * 256 + threadIdx.x;
    if (t >= 81920) return;
    int j = t % 80;
    int rest = t / 80;
    int c = rest & 511;
    int b = rest >> 9;
    int s = pool[j];
    const int* a = adj + s * 4;
    float m = 0.0f;
#pragma unroll
    for (int i = 0; i < 4; i++) {
        float v = (float)in[((size_t)b * 320 + a[i]) * 512 + c];
        m = fmaxf(m, v);
    }
    out[t] = m;
}

// ---------------------------------------------------------------------------
extern "C" void kernel_launch(void* const* d_in, const int* in_sizes, int n_in,
                              void* d_out, int out_size, void* d_ws, size_t ws_size,
                              hipStream_t stream)
{
    const float* x = (const float*)d_in[0];
    const int* convT[5]; const int* adjT[5]; const int* poolT[5];
    for (int l = 0; l < 5; l++) {
        convT[l] = (const int*)d_in[1 + 3 * l];
        adjT[l]  = (const int*)d_in[2 + 3 * l];
        poolT[l] = (const int*)d_in[3 + 3 * l];
    }
    const float* W[13]; const float* Bs[13];
    for (int i = 0; i < 13; i++) {
        W[i]  = (const float*)d_in[16 + 2 * i];
        Bs[i] = (const float*)d_in[17 + 2 * i];
    }

    // ws = 256MB. Non-overlapping layout:
    bf16* wbf   = (bf16*)d_ws;                                // 32.7MB weights
    bf16* A     = (bf16*)((char*)d_ws + (40u << 20));         // 21MB activations
    bf16* Bb    = (bf16*)((char*)d_ws + (70u << 20));         // 21MB activations
    float* slabA = (float*)((char*)d_ws + (100u << 20));      // split-K slabs
    float* slabB = (float*)((char*)d_ws + (130u << 20));

    static const int woff[13] = {0, 0, 40960, 122880, 286720, 614400, 1269760,
                                 1925120, 3235840, 5857280, 8478720, 11100160, 13721600};

    prep_w<<<dim3(817152 / 256), dim3(256), 0, stream>>>(
        W[1], W[2], W[3], W[4], W[5], W[6], W[7], W[8], W[9], W[10], W[11], W[12], wbf);

    conv0_kernel<<<dim3(640), dim3(256), 0, stream>>>(x, W[0], Bs[0], convT[0], A);

    const int PO3 = 2560 * 512;
    const int PO4 = 640 * 512;

    // level 0: register-direct X + one-shot LDS W (zero K-loop barriers)
    conv_reg64<<<dim3(1280), dim3(256), 0, stream>>>(
        A, wbf + woff[1], Bs[1], convT[0], Bb, 81920);
    pool_kernel<<<dim3(640, 2), dim3(256), 0, stream>>>(Bb, adjT[0], poolT[0], A, 81920, 20480, 3);
    // level 1  (grid.x = 640: 640*64 = 40960 = 2*N positions)
    conv_p<64, 64, 64, 2, 2><<<dim3(640, 2, 1), dim3(256), 0, stream>>>(
        A, wbf + woff[2], Bs[2], convT[1], Bb, nullptr, 20480, 128, 1, 0);
    conv_p<128, 64, 64, 2, 2><<<dim3(640, 2, 1), dim3(256), 0, stream>>>(
        Bb, wbf + woff[3], Bs[3], convT[1], A, nullptr, 20480, 128, 1, 0);
    pool_kernel<<<dim3(320, 2), dim3(256), 0, stream>>>(A, adjT[1], poolT[1], Bb, 20480, 5120, 4);
    // level 2
    conv_p<128, 64, 64, 2, 2><<<dim3(160, 4, 1), dim3(256), 0, stream>>>(
        Bb, wbf + woff[4], Bs[4], convT[2], A, nullptr, 5120, 256, 1, 0);
    conv_p<256, 64, 64, 2, 2><<<dim3(160, 4, 1), dim3(256), 0, stream>>>(
        A, wbf + woff[5], Bs[5], convT[2], Bb, nullptr, 5120, 256, 1, 0);
    conv_p<256, 64, 64, 2, 2><<<dim3(160, 4, 1), dim3(256), 0, stream>>>(
        Bb, wbf + woff[6], Bs[6], convT[2], A, nullptr, 5120, 256, 1, 0);
    pool_kernel<<<dim3(160, 2), dim3(256), 0, stream>>>(A, adjT[2], poolT[2], Bb, 5120, 1280, 5);
    // level 3 (split-K S=2 -> 640 blocks)
    conv_p<256, 64, 64, 2, 2><<<dim3(40, 8, 2), dim3(256), 0, stream>>>(
        Bb, wbf + woff[7], Bs[7], convT[3], nullptr, slabA, 1280, 512, 2, PO3);
    epi_reduce<<<dim3(PO3 / 1024), dim3(256), 0, stream>>>(slabA, Bs[7], A, PO3, 511, 2);
    conv_p<512, 64, 64, 2, 2><<<dim3(40, 8, 2), dim3(256), 0, stream>>>(
        A, wbf + woff[8], Bs[8], convT[3], nullptr, slabB, 1280, 512, 2, PO3);
    epi_reduce<<<dim3(PO3 / 1024), dim3(256), 0, stream>>>(slabB, Bs[8], Bb, PO3, 511, 2);
    conv_p<512, 64, 64, 2, 2><<<dim3(40, 8, 2), dim3(256), 0, stream>>>(
        Bb, wbf + woff[9], Bs[9], convT[3], nullptr, slabA, 1280, 512, 2, PO3);
    epi_reduce<<<dim3(PO3 / 1024), dim3(256), 0, stream>>>(slabA, Bs[9], A, PO3, 511, 2);
    pool_kernel<<<dim3(80, 2), dim3(256), 0, stream>>>(A, adjT[3], poolT[3], Bb, 1280, 320, 6);
    // level 4 (split-K S=8 -> 640 blocks)
    conv_p<512, 64, 64, 2, 2><<<dim3(10, 8, 8), dim3(256), 0, stream>>>(
        Bb, wbf + woff[10], Bs[10], convT[4], nullptr, slabA, 320, 512, 8, PO4);
    epi_reduce<<<dim3(PO4 / 1024), dim3(256), 0, stream>>>(slabA, Bs[10], A, PO4, 511, 8);
    conv_p<512, 64, 64, 2, 2><<<dim3(10, 8, 8), dim3(256), 0, stream>>>(
        A, wbf + woff[11], Bs[11], convT[4], nullptr, slabB, 320, 512, 8, PO4);
    epi_reduce<<<dim3(PO4 / 1024), dim3(256), 0, stream>>>(slabB, Bs[11], Bb, PO4, 511, 8);
    conv_p<512, 64, 64, 2, 2><<<dim3(10, 8, 8), dim3(256), 0, stream>>>(
        Bb, wbf + woff[12], Bs[12], convT[4], nullptr, slabA, 320, 512, 8, PO4);
    epi_reduce<<<dim3(PO4 / 1024), dim3(256), 0, stream>>>(slabA, Bs[12], A, PO4, 511, 8);

    final_pool<<<dim3(320), dim3(256), 0, stream>>>(A, adjT[4], poolT[4], (float*)d_out);
}